// Round 5
// baseline (274.752 us; speedup 1.0000x reference)
//
#include <hip/hip_runtime.h>

#define NTOK 16384
#define BATCH 4

typedef __attribute__((ext_vector_type(8))) short bf16x8;
typedef __attribute__((ext_vector_type(8))) unsigned short ushort8;
typedef __attribute__((ext_vector_type(4))) float f32x4;

__device__ __forceinline__ unsigned short f2bf(float f) {
  union { float f; unsigned int u; } c; c.f = f;
  unsigned int r = c.u + 0x7fff + ((c.u >> 16) & 1);  // RTN-even
  return (unsigned short)(r >> 16);
}

__global__ __launch_bounds__(256) void zero_f(float* __restrict__ p, int n) {
  int i = blockIdx.x * 256 + threadIdx.x;
  if (i < n) p[i] = 0.f;
}

// fp32 -> bf16 pre-pass: voxel (2097152 grp) then A (524288 grp)
__global__ __launch_bounds__(256) void convx2(const float* __restrict__ voxel,
                                              const float* __restrict__ A,
                                              unsigned short* __restrict__ xb,
                                              unsigned short* __restrict__ Ab) {
  for (int i = blockIdx.x * 256 + threadIdx.x; i < 2621440; i += gridDim.x * 256) {
    const float* src; unsigned short* dst; int j;
    if (i < 2097152) { j = i; src = voxel; dst = xb; }
    else { j = i - 2097152; src = A; dst = Ab; }
    float4 a = *(const float4*)(src + 8 * (size_t)j);
    float4 b = *(const float4*)(src + 8 * (size_t)j + 4);
    ushort8 o;
    o[0] = f2bf(a.x); o[1] = f2bf(a.y); o[2] = f2bf(a.z); o[3] = f2bf(a.w);
    o[4] = f2bf(b.x); o[5] = f2bf(b.y); o[6] = f2bf(b.z); o[7] = f2bf(b.w);
    *(ushort8*)(dst + 8 * (size_t)j) = o;
  }
}

// transpose+convert weights; block 512 converts cb -> cbbT[l][j] = cb[j][l]
__global__ __launch_bounds__(256) void convw(const float* __restrict__ w_qkv,
                                             const float* __restrict__ w_proj,
                                             const float* __restrict__ cb,
                                             unsigned short* __restrict__ wqT,
                                             unsigned short* __restrict__ wpT,
                                             unsigned short* __restrict__ cbbT) {
  int n = blockIdx.x, k = threadIdx.x;
  if (n < 256) wqT[n * 256 + k] = f2bf(w_qkv[(size_t)k * 768 + n]);
  else if (n < 512) wpT[(n - 256) * 256 + k] = f2bf(w_proj[(size_t)k * 256 + (n - 256)]);
  else if (n == 512 && k < 64) {
    for (int j = 0; j < 64; ++j) cbbT[k * 64 + j] = f2bf(cb[j * 64 + k]);
  }
}

// C[M,N] = A[M,K=256] @ BT[N,K]^T (+bias). MFMA bf16. Tile 128x128, 4 waves.
// K MUST be 256. Single-buffer LDS (36864 B), 2-deep register prefetch
// (single HBM latency exposure), LDS-staged coalesced C writeout.
template <int ADD_BIAS, int C_BF16>
__global__ __launch_bounds__(256, 3) void gemm_mfma(const unsigned short* __restrict__ Ab,
                                                    const unsigned short* __restrict__ BT,
                                                    const float* __restrict__ bias,
                                                    void* __restrict__ Cv,
                                                    int N, int K, int lda) {
  __shared__ __align__(16) unsigned short smem[2][128][72];
  const int tid = threadIdx.x;
  int bx, by;
  if ((gridDim.y & 7) == 0) {  // XCD swizzle only when grid.y divisible by 8
    int flat = blockIdx.y * gridDim.x + blockIdx.x;
    int xc = flat & 7, t = flat >> 3;
    int gx = gridDim.x, ypx = gridDim.y >> 3;
    bx = t % gx; by = xc * ypx + t / gx;
  } else { bx = blockIdx.x; by = blockIdx.y; }
  const int bn = bx * 128, bm = by * 128;
  const int lane = tid & 63;
  const int wv = tid >> 6;
  const int wm = wv & 1, wn = wv >> 1;
  const int m16 = lane & 15, quad = lane >> 4;

  const int srow = tid >> 1;
  const int scol = (tid & 1) * 32;

  const unsigned short* ga = Ab + (size_t)(bm + srow) * lda + scol;
  const unsigned short* gb = BT + (size_t)(bn + srow) * K + scol;

  // 2-deep staging: tiles kt and kt+1 in regs
  ushort8 ra[2][4], rb[2][4];
#pragma unroll
  for (int kt = 0; kt < 2; ++kt)
#pragma unroll
    for (int i = 0; i < 4; ++i) {
      ra[kt][i] = *(const ushort8*)(ga + kt * 64 + 8 * i);
      rb[kt][i] = *(const ushort8*)(gb + kt * 64 + 8 * i);
    }

  f32x4 acc[4][4];
#pragma unroll
  for (int r = 0; r < 4; ++r)
#pragma unroll
    for (int c = 0; c < 4; ++c) acc[r][c] = (f32x4){0.f, 0.f, 0.f, 0.f};

#pragma unroll
  for (int kt = 0; kt < 4; ++kt) {
    const int sb = kt & 1;
    if (kt > 0) __syncthreads();  // prior tile's frag reads done
#pragma unroll
    for (int i = 0; i < 4; ++i) {
      *(ushort8*)&smem[0][srow][scol + 8 * i] = ra[sb][i];
      *(ushort8*)&smem[1][srow][scol + 8 * i] = rb[sb][i];
    }
    __syncthreads();
    if (kt < 2) {  // prefetch tile kt+2 into the reg slot just freed
#pragma unroll
      for (int i = 0; i < 4; ++i) {
        ra[sb][i] = *(const ushort8*)(ga + (kt + 2) * 64 + 8 * i);
        rb[sb][i] = *(const ushort8*)(gb + (kt + 2) * 64 + 8 * i);
      }
    }
#pragma unroll
    for (int ks = 0; ks < 64; ks += 32) {
      bf16x8 af[4], bf[4];
#pragma unroll
      for (int r = 0; r < 4; ++r)
        af[r] = *(const bf16x8*)&smem[0][wm * 64 + r * 16 + m16][ks + quad * 8];
#pragma unroll
      for (int c = 0; c < 4; ++c)
        bf[c] = *(const bf16x8*)&smem[1][wn * 64 + c * 16 + m16][ks + quad * 8];
#pragma unroll
      for (int r = 0; r < 4; ++r)
#pragma unroll
        for (int c = 0; c < 4; ++c)
          acc[r][c] = __builtin_amdgcn_mfma_f32_16x16x32_bf16(af[r], bf[c], acc[r][c], 0, 0, 0);
    }
  }

  // ---- staged coalesced writeout: 2 passes of 64 rows via LDS ----
  float bv[4];
  if (ADD_BIAS) {
#pragma unroll
    for (int c = 0; c < 4; ++c) bv[c] = bias[bn + wn * 64 + c * 16 + m16];
  }
  const int lrD = tid >> 2, cch = (tid & 3) * 32;
  unsigned short* Csh = (unsigned short*)smem;  // [64][136] bf16 path
  float* Csf = (float*)smem;                    // [64][132] f32 path
#pragma unroll
  for (int p = 0; p < 2; ++p) {
    __syncthreads();
    if (wm == p) {
#pragma unroll
      for (int r = 0; r < 4; ++r) {
        int lr0 = r * 16 + quad * 4;
#pragma unroll
        for (int c = 0; c < 4; ++c) {
          int col = wn * 64 + c * 16 + m16;
#pragma unroll
          for (int i = 0; i < 4; ++i) {
            float v = acc[r][c][i] + (ADD_BIAS ? bv[c] : 0.f);
            if (C_BF16) Csh[(lr0 + i) * 136 + col] = f2bf(v);
            else Csf[(lr0 + i) * 132 + col] = v;
          }
        }
      }
    }
    __syncthreads();
    if (C_BF16) {
      unsigned short* gp = (unsigned short*)Cv + (size_t)(bm + p * 64 + lrD) * N + bn + cch;
      const unsigned short* sp = Csh + lrD * 136 + cch;
      ushort8 t0 = *(const ushort8*)(sp + 0);
      ushort8 t1 = *(const ushort8*)(sp + 8);
      ushort8 t2 = *(const ushort8*)(sp + 16);
      ushort8 t3 = *(const ushort8*)(sp + 24);
      *(ushort8*)(gp + 0) = t0;
      *(ushort8*)(gp + 8) = t1;
      *(ushort8*)(gp + 16) = t2;
      *(ushort8*)(gp + 24) = t3;
    } else {
      float* gp = (float*)Cv + (size_t)(bm + p * 64 + lrD) * N + bn + cch;
      const float* sp = Csf + lrD * 132 + cch;
      float4 t[8];
#pragma unroll
      for (int u = 0; u < 8; ++u) t[u] = *(const float4*)(sp + 4 * u);
#pragma unroll
      for (int u = 0; u < 8; ++u) *(float4*)(gp + 4 * u) = t[u];
    }
  }
}

// ---- pool X via MFMA: part[b][tch][cl 64][ch 256] over 256-token chunks.
// pooledX = A^T @ X; Wk/Wv applied AFTER pooling (linearity). ----
__global__ __launch_bounds__(256) void pool_mfma(const unsigned short* __restrict__ Ab,
                                                 const unsigned short* __restrict__ xb,
                                                 float* __restrict__ part) {
  __shared__ unsigned short At[64][40];
  __shared__ unsigned short Xt[128][40];
  const int tid = threadIdx.x;
  const int tch = blockIdx.x, cblk = blockIdx.y, b = blockIdx.z;
  const int w = tid >> 6, lane = tid & 63;
  const int m16 = lane & 15, quad = lane >> 4;
  const size_t row0 = (size_t)b * NTOK + (size_t)tch * 256;
  const int cb0 = cblk * 128;
  const int tokL = tid & 31, gA = tid >> 5;

  f32x4 acc[4][2];
#pragma unroll
  for (int r = 0; r < 4; ++r)
#pragma unroll
    for (int c = 0; c < 2; ++c) acc[r][c] = (f32x4){0.f, 0.f, 0.f, 0.f};

  ushort8 px[2], pa;
  auto loadG = [&](int t0) {
#pragma unroll
    for (int u = 0; u < 2; ++u) {
      int idx = tid + u * 256;
      int tok = idx & 31, g = idx >> 5;
      px[u] = *(const ushort8*)(xb + (row0 + t0 + tok) * 256 + cb0 + g * 8);
    }
    pa = *(const ushort8*)(Ab + (row0 + t0 + tokL) * 64 + gA * 8);
  };
  loadG(0);

  for (int ks = 0; ks < 8; ++ks) {
    __syncthreads();
#pragma unroll
    for (int u = 0; u < 2; ++u) {
      int idx = tid + u * 256;
      int tok = idx & 31, g = idx >> 5;
#pragma unroll
      for (int i = 0; i < 8; ++i) Xt[g * 8 + i][tok] = (unsigned short)px[u][i];
    }
#pragma unroll
    for (int i = 0; i < 8; ++i) At[gA * 8 + i][tokL] = (unsigned short)pa[i];
    __syncthreads();
    if (ks + 1 < 8) loadG((ks + 1) * 32);
    bf16x8 af[4], bfr[2];
#pragma unroll
    for (int r = 0; r < 4; ++r) af[r] = *(const bf16x8*)&At[r * 16 + m16][quad * 8];
#pragma unroll
    for (int c = 0; c < 2; ++c) bfr[c] = *(const bf16x8*)&Xt[w * 32 + c * 16 + m16][quad * 8];
#pragma unroll
    for (int r = 0; r < 4; ++r)
#pragma unroll
      for (int c = 0; c < 2; ++c)
        acc[r][c] = __builtin_amdgcn_mfma_f32_16x16x32_bf16(af[r], bfr[c], acc[r][c], 0, 0, 0);
  }

  float* pp = part + ((size_t)(b * 64 + tch) * 64) * 256 + cb0;
#pragma unroll
  for (int r = 0; r < 4; ++r)
#pragma unroll
    for (int c = 0; c < 2; ++c)
#pragma unroll
      for (int i = 0; i < 4; ++i) {
        int cl = r * 16 + quad * 4 + i;
        int ch = w * 32 + c * 16 + m16;
        pp[(size_t)cl * 256 + ch] = acc[r][c][i];
      }
}

// reduce 64 chunks -> pooledX[b*64+cl][ch] F32 (already /denom).
__global__ __launch_bounds__(256) void pool2(const float* __restrict__ part,
                                             const float* __restrict__ asum,
                                             float* __restrict__ pooledX) {
  int id = blockIdx.x * 256 + threadIdx.x;  // 0..65535
  int c = id & 255, cl = (id >> 8) & 63, b = id >> 14;
  const float* pp = part + ((size_t)(b * 64) * 64 + cl) * 256 + c;
  float s = 0.f;
#pragma unroll 4
  for (int t = 0; t < 64; ++t) s += pp[(size_t)t * 16384];
  float denom = asum[b * 64 + cl] + 1e-8f;
  pooledX[(size_t)(b * 64 + cl) * 256 + c] = s / denom;
}

// fp32 K/V mini-GEMM: [kc|vc](b,cl,:) = pooledX(b,cl,:) @ w_qkv[:,256:768].
// One block per (b,cl); full f32 accumulate, single bf16 rounding at the end.
__global__ __launch_bounds__(256) void kvgemm(const float* __restrict__ pooledX,
                                              const float* __restrict__ w_qkv,
                                              unsigned short* __restrict__ kcb,
                                              unsigned short* __restrict__ vcbT) {
  __shared__ float px[256];
  const int bc = blockIdx.x;  // b*64 + cl
  const int b = bc >> 6, cl = bc & 63;
  const int tid = threadIdx.x;
  px[tid] = pooledX[(size_t)bc * 256 + tid];
  __syncthreads();
  float accK = 0.f, accV = 0.f;
#pragma unroll 8
  for (int k = 0; k < 256; ++k) {
    float x = px[k];
    accK = fmaf(x, w_qkv[(size_t)k * 768 + 256 + tid], accK);
    accV = fmaf(x, w_qkv[(size_t)k * 768 + 512 + tid], accV);
  }
  int h = tid >> 5, d = tid & 31;
  kcb[(((size_t)b * 8 + h) * 64 + cl) * 32 + d] = f2bf(accK * 0.17677669529663687f);
  vcbT[(((size_t)b * 8 + h) * 32 + d) * 64 + cl] = f2bf(accV);
}

__global__ __launch_bounds__(256) void asum_kernel(const float* __restrict__ A,
                                                   float* __restrict__ asum) {
  __shared__ float red[4][64];
  const int ch = blockIdx.x, b = blockIdx.y;
  const int jq = threadIdx.x >> 6, k = threadIdx.x & 63;
  const size_t row0 = (size_t)b * NTOK + (size_t)ch * 256;
  const float* ap = A + (row0 + jq) * 64 + k;
  float s = 0.f;
#pragma unroll 4
  for (int j = 0; j < 64; ++j) s += ap[(size_t)j * 256];
  red[jq][k] = s;
  __syncthreads();
  if (threadIdx.x < 64) {
    float v = red[0][k] + red[1][k] + red[2][k] + red[3][k];
    atomicAdd(&asum[b * 64 + k], v);
  }
}

// ---- fused attention: 128 tokens x 4 heads per block; bias = A@cbT in regs;
// per head: scores (K=32 MFMA), in-register softmax, PV MFMA. Q in qb (lda 256),
// x written in place over Q. ----
__global__ __launch_bounds__(256) void attn_mfma(const unsigned short* __restrict__ Ab,
                                                 unsigned short* __restrict__ qb,
                                                 const unsigned short* __restrict__ kcb,
                                                 const unsigned short* __restrict__ vcbT,
                                                 const unsigned short* __restrict__ cbbT) {
  __shared__ __align__(16) char lds[38400];
  unsigned short* PA  = (unsigned short*)lds;            // [128][72]: A tile, then P
  unsigned short* Qs  = (unsigned short*)(lds + 18432);  // [128][40]
  unsigned short* KCs = (unsigned short*)(lds + 28672);  // [64][40]
  unsigned short* VTs = (unsigned short*)(lds + 33792);  // [32][72]
  unsigned short* CBs = (unsigned short*)(lds + 28672);  // [64][72] alias KC+VT

  const int tid = threadIdx.x;
  const int nb = blockIdx.x, hq = blockIdx.y, b = blockIdx.z;
  const int h0 = hq * 4;
  const int w = tid >> 6, lane = tid & 63;
  const int m16 = lane & 15, quad = lane >> 4;
  const size_t row0 = (size_t)b * NTOK + (size_t)nb * 128;

  const int r2 = tid >> 1, half = tid & 1;
  const int l4 = tid >> 2, s3 = tid & 3;
  const int d8 = tid >> 3, s7 = tid & 7;

  ushort8 rA[4], rcb[2];
  {
    const unsigned short* ap = Ab + (row0 + r2) * 64 + half * 32;
#pragma unroll
    for (int u = 0; u < 4; ++u) rA[u] = *(const ushort8*)(ap + 8 * u);
    const unsigned short* cp = cbbT + l4 * 64 + s3 * 16;
    rcb[0] = *(const ushort8*)cp;
    rcb[1] = *(const ushort8*)(cp + 8);
  }
  ushort8 rq[2][2], rkc[2], rvt[2];
  {
    const unsigned short* qp = qb + (row0 + r2) * 256 + h0 * 32 + half * 16;
    rq[0][0] = *(const ushort8*)qp;
    rq[0][1] = *(const ushort8*)(qp + 8);
    rkc[0] = *(const ushort8*)(kcb + (((size_t)b * 8 + h0) * 64 + l4) * 32 + s3 * 8);
    rvt[0] = *(const ushort8*)(vcbT + (((size_t)b * 8 + h0) * 32 + d8) * 64 + s7 * 8);
  }
#pragma unroll
  for (int u = 0; u < 4; ++u) *(ushort8*)&PA[r2 * 72 + half * 32 + 8 * u] = rA[u];
  *(ushort8*)&CBs[l4 * 72 + s3 * 16] = rcb[0];
  *(ushort8*)&CBs[l4 * 72 + s3 * 16 + 8] = rcb[1];
  __syncthreads();

  f32x4 bacc[2][4];
#pragma unroll
  for (int rt = 0; rt < 2; ++rt)
#pragma unroll
    for (int nt = 0; nt < 4; ++nt) bacc[rt][nt] = (f32x4){0.f, 0.f, 0.f, 0.f};
#pragma unroll
  for (int ks = 0; ks < 64; ks += 32) {
    bf16x8 af[2], bf[4];
#pragma unroll
    for (int rt = 0; rt < 2; ++rt)
      af[rt] = *(const bf16x8*)&PA[(w * 32 + rt * 16 + m16) * 72 + ks + quad * 8];
#pragma unroll
    for (int nt = 0; nt < 4; ++nt)
      bf[nt] = *(const bf16x8*)&CBs[(nt * 16 + m16) * 72 + ks + quad * 8];
#pragma unroll
    for (int rt = 0; rt < 2; ++rt)
#pragma unroll
      for (int nt = 0; nt < 4; ++nt)
        bacc[rt][nt] = __builtin_amdgcn_mfma_f32_16x16x32_bf16(af[rt], bf[nt], bacc[rt][nt], 0, 0, 0);
  }
  __syncthreads();

#pragma unroll
  for (int hh = 0; hh < 4; ++hh) {
    const int h = h0 + hh;
    const int cur = hh & 1;
    *(ushort8*)&Qs[r2 * 40 + half * 16] = rq[cur][0];
    *(ushort8*)&Qs[r2 * 40 + half * 16 + 8] = rq[cur][1];
    *(ushort8*)&KCs[l4 * 40 + s3 * 8] = rkc[cur];
    *(ushort8*)&VTs[d8 * 72 + s7 * 8] = rvt[cur];
    if (hh < 3) {
      const int h1 = h + 1;
      const unsigned short* qp = qb + (row0 + r2) * 256 + h1 * 32 + half * 16;
      rq[cur ^ 1][0] = *(const ushort8*)qp;
      rq[cur ^ 1][1] = *(const ushort8*)(qp + 8);
      rkc[cur ^ 1] = *(const ushort8*)(kcb + (((size_t)b * 8 + h1) * 64 + l4) * 32 + s3 * 8);
      rvt[cur ^ 1] = *(const ushort8*)(vcbT + (((size_t)b * 8 + h1) * 32 + d8) * 64 + s7 * 8);
    }
    __syncthreads();

    f32x4 acc[2][4];
#pragma unroll
    for (int rt = 0; rt < 2; ++rt)
#pragma unroll
      for (int nt = 0; nt < 4; ++nt) acc[rt][nt] = bacc[rt][nt];
    {
      bf16x8 af[2], bf[4];
#pragma unroll
      for (int rt = 0; rt < 2; ++rt)
        af[rt] = *(const bf16x8*)&Qs[(w * 32 + rt * 16 + m16) * 40 + quad * 8];
#pragma unroll
      for (int nt = 0; nt < 4; ++nt)
        bf[nt] = *(const bf16x8*)&KCs[(nt * 16 + m16) * 40 + quad * 8];
#pragma unroll
      for (int rt = 0; rt < 2; ++rt)
#pragma unroll
        for (int nt = 0; nt < 4; ++nt)
          acc[rt][nt] = __builtin_amdgcn_mfma_f32_16x16x32_bf16(af[rt], bf[nt], acc[rt][nt], 0, 0, 0);
    }

#pragma unroll
    for (int rt = 0; rt < 2; ++rt) {
      f32x4 mxv, sv;
#pragma unroll
      for (int i = 0; i < 4; ++i)
        mxv[i] = fmaxf(fmaxf(acc[rt][0][i], acc[rt][1][i]),
                       fmaxf(acc[rt][2][i], acc[rt][3][i]));
#pragma unroll
      for (int msk = 1; msk < 16; msk <<= 1)
#pragma unroll
        for (int i = 0; i < 4; ++i) mxv[i] = fmaxf(mxv[i], __shfl_xor(mxv[i], msk));
#pragma unroll
      for (int i = 0; i < 4; ++i) sv[i] = 0.f;
#pragma unroll
      for (int nt = 0; nt < 4; ++nt)
#pragma unroll
        for (int i = 0; i < 4; ++i) {
          float e = __expf(acc[rt][nt][i] - mxv[i]);
          acc[rt][nt][i] = e;
          sv[i] += e;
        }
#pragma unroll
      for (int msk = 1; msk < 16; msk <<= 1)
#pragma unroll
        for (int i = 0; i < 4; ++i) sv[i] += __shfl_xor(sv[i], msk);
#pragma unroll
      for (int i = 0; i < 4; ++i) sv[i] = 1.f / sv[i];
#pragma unroll
      for (int nt = 0; nt < 4; ++nt)
#pragma unroll
        for (int i = 0; i < 4; ++i)
          PA[(w * 32 + rt * 16 + quad * 4 + i) * 72 + nt * 16 + m16] =
              f2bf(acc[rt][nt][i] * sv[i]);
    }

    f32x4 acc2[2][2];
#pragma unroll
    for (int rt = 0; rt < 2; ++rt)
#pragma unroll
      for (int nt = 0; nt < 2; ++nt) acc2[rt][nt] = (f32x4){0.f, 0.f, 0.f, 0.f};
#pragma unroll
    for (int kch = 0; kch < 64; kch += 32) {
      bf16x8 af2[2], bf2[2];
#pragma unroll
      for (int rt = 0; rt < 2; ++rt)
        af2[rt] = *(const bf16x8*)&PA[(w * 32 + rt * 16 + m16) * 72 + kch + quad * 8];
#pragma unroll
      for (int nt = 0; nt < 2; ++nt)
        bf2[nt] = *(const bf16x8*)&VTs[(nt * 16 + m16) * 72 + kch + quad * 8];
#pragma unroll
      for (int rt = 0; rt < 2; ++rt)
#pragma unroll
        for (int nt = 0; nt < 2; ++nt)
          acc2[rt][nt] = __builtin_amdgcn_mfma_f32_16x16x32_bf16(af2[rt], bf2[nt], acc2[rt][nt], 0, 0, 0);
    }

#pragma unroll
    for (int rt = 0; rt < 2; ++rt)
#pragma unroll
      for (int nt = 0; nt < 2; ++nt)
#pragma unroll
        for (int i = 0; i < 4; ++i) {
          int tr = w * 32 + rt * 16 + quad * 4 + i;
          int d = nt * 16 + m16;
          qb[(row0 + tr) * 256 + h * 32 + d] = f2bf(acc2[rt][nt][i]);
        }
    __syncthreads();
  }
}

extern "C" void kernel_launch(void* const* d_in, const int* in_sizes, int n_in,
                              void* d_out, int out_size, void* d_ws, size_t ws_size,
                              hipStream_t stream) {
  const float* voxel  = (const float*)d_in[0];
  const float* A      = (const float*)d_in[1];
  const float* w_qkv  = (const float*)d_in[2];
  const float* w_proj = (const float*)d_in[3];
  const float* b_proj = (const float*)d_in[4];
  const float* cb     = (const float*)d_in[5];
  float* out = (float*)d_out;
  (void)in_sizes; (void)n_in; (void)out_size; (void)ws_size;

  // ws layout (byte offsets / sizes):
  // qb        0         33554432   (4*16384*256 bf16)
  // xb        33554432  33554432
  // part      67108864  16777216   (4*64*64*256 f32)
  // asum      83886080  1024
  // pooledXf  83887104  262144     (4*64*256 f32)
  // wqT       84149248  131072
  // wpT       84280320  131072
  // kcb       84411392  131072    <- FULL size: 4*8*64*32 shorts = 131072 B
  // vcbT      84542464  131072    <- FULL size (round3/4 under-allocated: bug)
  // cbbT      84673536  8192
  char* wsb = (char*)d_ws;
  unsigned short* qb       = (unsigned short*)wsb;
  unsigned short* xb       = (unsigned short*)(wsb + 33554432);
  float* part              = (float*)(wsb + 67108864);
  float* asum              = (float*)(wsb + 83886080);
  float* pooledXf          = (float*)(wsb + 83887104);
  unsigned short* wqT      = (unsigned short*)(wsb + 84149248);
  unsigned short* wpT      = (unsigned short*)(wsb + 84280320);
  unsigned short* kcb      = (unsigned short*)(wsb + 84411392);
  unsigned short* vcbT     = (unsigned short*)(wsb + 84542464);
  unsigned short* cbbT     = (unsigned short*)(wsb + 84673536);
  // Ab (bf16 A, 8 MB) parked in d_out: dead before the final GEMM writes out
  unsigned short* Ab = (unsigned short*)d_out;

  zero_f<<<1, 256, 0, stream>>>(asum, 256);
  convw<<<513, 256, 0, stream>>>(w_qkv, w_proj, cb, wqT, wpT, cbbT);
  convx2<<<2048, 256, 0, stream>>>(voxel, A, xb, Ab);

  // Q only: qb(bf16) = xb @ Wq
  gemm_mfma<0, 1><<<dim3(2, 512), 256, 0, stream>>>(xb, wqT, nullptr, qb,
                                                    256, 256, 256);

  asum_kernel<<<dim3(64, BATCH), 256, 0, stream>>>(A, asum);
  // pooledX = A^T @ X (per 256-token chunk partials), f32 throughout
  pool_mfma<<<dim3(64, 2, BATCH), 256, 0, stream>>>(Ab, xb, part);
  pool2<<<256, 256, 0, stream>>>(part, asum, pooledXf);
  // K/V clusters in fp32 from pooledX and original w_qkv
  kvgemm<<<256, 256, 0, stream>>>(pooledXf, w_qkv, kcb, vcbT);

  // fused attention: 128 tokens x 4 heads per block; x overwrites Q in qb
  attn_mfma<<<dim3(NTOK / 128, 2, BATCH), 256, 0, stream>>>(Ab, qb, kcb, vcbT, cbbT);

  // out = x @ w_proj + b_proj (x bf16 in qb, lda 256)
  gemm_mfma<1, 0><<<dim3(2, 512), 256, 0, stream>>>(qb, wpT, b_proj, out,
                                                    256, 256, 256);
}